// Round 1
// baseline (1974.088 us; speedup 1.0000x reference)
//
#include <hip/hip_runtime.h>

#define NEG_SLOPE 0.2f

__device__ __forceinline__ float lrelu(float v) {
    return v > 0.0f ? v : NEG_SLOPE * v;
}

// C0 = A @ W0, C1 = A @ W1   (A: [N,128], W: [128,128], C: [N,128])
// block 256 threads, tile 64 rows x 128 cols, K-chunks of 32.
__global__ __launch_bounds__(256) void gemm2_kernel(
    const float* __restrict__ A,
    const float* __restrict__ W0, const float* __restrict__ W1,
    float* __restrict__ C0, float* __restrict__ C1, int N)
{
    const float* W = blockIdx.y ? W1 : W0;
    float* C = blockIdx.y ? C1 : C0;

    __shared__ float lds_a[64][33];    // +1 pad breaks bank aliasing on the a-broadcast reads
    __shared__ float lds_w[32][128];

    const int tid = threadIdx.x;
    const int row0 = blockIdx.x * 64;
    const int tx = tid & 15;    // col group: cols tx*8 .. tx*8+7
    const int ty = tid >> 4;    // row group: rows ty*4 .. ty*4+3

    float acc[4][8];
#pragma unroll
    for (int i = 0; i < 4; i++)
#pragma unroll
        for (int j = 0; j < 8; j++) acc[i][j] = 0.0f;

    for (int k0 = 0; k0 < 128; k0 += 32) {
        // A tile: 64 rows x 32 cols = 512 float4 loads, 2 per thread
        {
            int idx = tid;
#pragma unroll
            for (int rep = 0; rep < 2; rep++, idx += 256) {
                int r  = idx >> 3;
                int c4 = idx & 7;
                int gr = row0 + r;
                float4 v = make_float4(0.f, 0.f, 0.f, 0.f);
                if (gr < N) v = *(const float4*)(A + (size_t)gr * 128 + k0 + c4 * 4);
                *(float4*)&lds_a[r][c4 * 4] = v;
            }
        }
        // W tile: 32 rows x 128 cols = 1024 float4 loads, 4 per thread
        {
            int idx = tid;
#pragma unroll
            for (int rep = 0; rep < 4; rep++, idx += 256) {
                int r  = idx >> 5;
                int c4 = idx & 31;
                *(float4*)&lds_w[r][c4 * 4] = *(const float4*)(W + (size_t)(k0 + r) * 128 + c4 * 4);
            }
        }
        __syncthreads();

#pragma unroll
        for (int kk = 0; kk < 32; kk++) {
            float a0 = lds_a[ty * 4 + 0][kk];
            float a1 = lds_a[ty * 4 + 1][kk];
            float a2 = lds_a[ty * 4 + 2][kk];
            float a3 = lds_a[ty * 4 + 3][kk];
            float w[8];
            *(float4*)&w[0] = *(float4*)&lds_w[kk][tx * 8];
            *(float4*)&w[4] = *(float4*)&lds_w[kk][tx * 8 + 4];
#pragma unroll
            for (int j = 0; j < 8; j++) {
                acc[0][j] += a0 * w[j];
                acc[1][j] += a1 * w[j];
                acc[2][j] += a2 * w[j];
                acc[3][j] += a3 * w[j];
            }
        }
        __syncthreads();
    }

#pragma unroll
    for (int i = 0; i < 4; i++) {
        int gr = row0 + ty * 4 + i;
        if (gr < N) {
            *(float4*)(C + (size_t)gr * 128 + tx * 8)     = make_float4(acc[i][0], acc[i][1], acc[i][2], acc[i][3]);
            *(float4*)(C + (size_t)gr * 128 + tx * 8 + 4) = make_float4(acc[i][4], acc[i][5], acc[i][6], acc[i][7]);
        }
    }
}

// out[n*128 + j] = bias[j]
__global__ __launch_bounds__(256) void bias_init_kernel(
    float* __restrict__ out, const float* __restrict__ bias, int total)
{
    int i = blockIdx.x * 256 + threadIdx.x;
    if (i < total) out[i] = bias[i & 127];
}

// One wave (64 lanes) per edge. Computes ex[e,h] = exp(s[e,h]) (no max-shift;
// mathematically identical alpha) and atomically accumulates denom[dst,h].
template <int H>
__global__ __launch_bounds__(256) void edge_scores_kernel(
    const float* __restrict__ xl, const float* __restrict__ xr,
    const float* __restrict__ att, const int* __restrict__ ei,
    float* __restrict__ ex, float* __restrict__ denom, int E, int Et)
{
    int e = blockIdx.x * 4 + (threadIdx.x >> 6);
    if (e >= Et) return;
    int lane = threadIdx.x & 63;

    int src, dst;
    if (e < E) { src = ei[e]; dst = ei[E + e]; }
    else       { src = e - E; dst = src; }

    float2 a = *(const float2*)(xl + (size_t)src * 128 + lane * 2);
    float2 b = *(const float2*)(xr + (size_t)dst * 128 + lane * 2);
    float t0 = lrelu(a.x + b.x);
    float t1 = lrelu(a.y + b.y);
    float p = t0 * att[lane * 2] + t1 * att[lane * 2 + 1];

    if (H == 2) {
        // per-half-wave reduction: lanes 0-31 = head 0, lanes 32-63 = head 1
#pragma unroll
        for (int m = 1; m <= 16; m <<= 1) p += __shfl_xor(p, m, 64);
        if ((lane & 31) == 0) {
            int head = lane >> 5;
            float v = expf(p);
            ex[(size_t)e * 2 + head] = v;
            atomicAdd(denom + (size_t)dst * 2 + head, v);
        }
    } else {
#pragma unroll
        for (int m = 1; m <= 32; m <<= 1) p += __shfl_xor(p, m, 64);
        if (lane == 0) {
            float v = expf(p);
            ex[e] = v;
            atomicAdd(denom + dst, v);
        }
    }
}

// One wave per edge: out[dst, h, c] += xl[src, h, c] * alpha[e, h]
template <int H>
__global__ __launch_bounds__(256) void aggregate_kernel(
    const float* __restrict__ xl, const float* __restrict__ ex,
    const float* __restrict__ denom, const int* __restrict__ ei,
    float* __restrict__ out, int E, int Et)
{
    int e = blockIdx.x * 4 + (threadIdx.x >> 6);
    if (e >= Et) return;
    int lane = threadIdx.x & 63;

    int src, dst;
    if (e < E) { src = ei[e]; dst = ei[E + e]; }
    else       { src = e - E; dst = src; }

    float alpha;
    if (H == 2) {
        int head = lane >> 5;
        alpha = ex[(size_t)e * 2 + head] / denom[(size_t)dst * 2 + head];
    } else {
        alpha = ex[e] / denom[dst];
    }

    float2 a = *(const float2*)(xl + (size_t)src * 128 + lane * 2);
    atomicAdd(out + (size_t)dst * 128 + lane * 2,     a.x * alpha);
    atomicAdd(out + (size_t)dst * 128 + lane * 2 + 1, a.y * alpha);
}

extern "C" void kernel_launch(void* const* d_in, const int* in_sizes, int n_in,
                              void* d_out, int out_size, void* d_ws, size_t ws_size,
                              hipStream_t stream)
{
    const float* x    = (const float*)d_in[0];
    const int*   ei   = (const int*)d_in[1];
    // d_in[2] = edge_attr: unused (reference default path ignores it)
    const float* Wl1  = (const float*)d_in[3];
    const float* Wr1  = (const float*)d_in[4];
    const float* att1 = (const float*)d_in[5];
    const float* b1   = (const float*)d_in[6];
    const float* Wl2  = (const float*)d_in[7];
    const float* Wr2  = (const float*)d_in[8];
    const float* att2 = (const float*)d_in[9];
    const float* b2   = (const float*)d_in[10];
    float* out = (float*)d_out;

    const int N  = in_sizes[0] / 128;
    const int E  = in_sizes[1] / 2;
    const int Et = E + N;   // with self-loops

    float* ws = (float*)d_ws;
    const size_t nf = (size_t)N * 128;
    float* xl    = ws;                       // N*128
    float* xr    = xl + nf;                  // N*128
    float* h     = xr + nf;                  // N*128  (layer-1 output)
    float* exb   = h + nf;                   // Et*2
    float* denom = exb + (size_t)Et * 2;     // N*2

    const int gemm_gx     = (N + 63) / 64;
    const int edge_blocks = (Et + 3) / 4;
    const int init_blocks = (int)((nf + 255) / 256);

    // ---- Layer 1: heads=2, ch=64 ----
    gemm2_kernel<<<dim3(gemm_gx, 2), 256, 0, stream>>>(x, Wl1, Wr1, xl, xr, N);
    hipMemsetAsync(denom, 0, (size_t)N * 2 * sizeof(float), stream);
    edge_scores_kernel<2><<<edge_blocks, 256, 0, stream>>>(xl, xr, att1, ei, exb, denom, E, Et);
    bias_init_kernel<<<init_blocks, 256, 0, stream>>>(h, b1, (int)nf);
    aggregate_kernel<2><<<edge_blocks, 256, 0, stream>>>(xl, exb, denom, ei, h, E, Et);

    // ---- Layer 2: heads=1, ch=128 ----
    gemm2_kernel<<<dim3(gemm_gx, 2), 256, 0, stream>>>(h, Wl2, Wr2, xl, xr, N);
    hipMemsetAsync(denom, 0, (size_t)N * sizeof(float), stream);
    edge_scores_kernel<1><<<edge_blocks, 256, 0, stream>>>(xl, xr, att2, ei, exb, denom, E, Et);
    bias_init_kernel<<<init_blocks, 256, 0, stream>>>(out, b2, (int)nf);
    aggregate_kernel<1><<<edge_blocks, 256, 0, stream>>>(xl, exb, denom, ei, out, E, Et);
}

// Round 2
// 629.786 us; speedup vs baseline: 3.1345x; 3.1345x over previous
//
#include <hip/hip_runtime.h>

#define NEG_SLOPE 0.2f

__device__ __forceinline__ float lrelu(float v) {
    return v > 0.0f ? v : NEG_SLOPE * v;
}

// ---------------------------------------------------------------------------
// GEMM: C0 = A @ W0, C1 = A @ W1   (A: [N,128], W: [128,128])
// ---------------------------------------------------------------------------
__global__ __launch_bounds__(256) void gemm2_kernel(
    const float* __restrict__ A,
    const float* __restrict__ W0, const float* __restrict__ W1,
    float* __restrict__ C0, float* __restrict__ C1, int N)
{
    const float* W = blockIdx.y ? W1 : W0;
    float* C = blockIdx.y ? C1 : C0;

    __shared__ float lds_a[64][33];
    __shared__ float lds_w[32][128];

    const int tid = threadIdx.x;
    const int row0 = blockIdx.x * 64;
    const int tx = tid & 15;
    const int ty = tid >> 4;

    float acc[4][8];
#pragma unroll
    for (int i = 0; i < 4; i++)
#pragma unroll
        for (int j = 0; j < 8; j++) acc[i][j] = 0.0f;

    for (int k0 = 0; k0 < 128; k0 += 32) {
        {
            int idx = tid;
#pragma unroll
            for (int rep = 0; rep < 2; rep++, idx += 256) {
                int r  = idx >> 3;
                int c4 = idx & 7;
                int gr = row0 + r;
                float4 v = make_float4(0.f, 0.f, 0.f, 0.f);
                if (gr < N) v = *(const float4*)(A + (size_t)gr * 128 + k0 + c4 * 4);
                *(float4*)&lds_a[r][c4 * 4] = v;
            }
        }
        {
            int idx = tid;
#pragma unroll
            for (int rep = 0; rep < 4; rep++, idx += 256) {
                int r  = idx >> 5;
                int c4 = idx & 31;
                *(float4*)&lds_w[r][c4 * 4] = *(const float4*)(W + (size_t)(k0 + r) * 128 + c4 * 4);
            }
        }
        __syncthreads();

#pragma unroll
        for (int kk = 0; kk < 32; kk++) {
            float a0 = lds_a[ty * 4 + 0][kk];
            float a1 = lds_a[ty * 4 + 1][kk];
            float a2 = lds_a[ty * 4 + 2][kk];
            float a3 = lds_a[ty * 4 + 3][kk];
            float w[8];
            *(float4*)&w[0] = *(float4*)&lds_w[kk][tx * 8];
            *(float4*)&w[4] = *(float4*)&lds_w[kk][tx * 8 + 4];
#pragma unroll
            for (int j = 0; j < 8; j++) {
                acc[0][j] += a0 * w[j];
                acc[1][j] += a1 * w[j];
                acc[2][j] += a2 * w[j];
                acc[3][j] += a3 * w[j];
            }
        }
        __syncthreads();
    }

#pragma unroll
    for (int i = 0; i < 4; i++) {
        int gr = row0 + ty * 4 + i;
        if (gr < N) {
            *(float4*)(C + (size_t)gr * 128 + tx * 8)     = make_float4(acc[i][0], acc[i][1], acc[i][2], acc[i][3]);
            *(float4*)(C + (size_t)gr * 128 + tx * 8 + 4) = make_float4(acc[i][4], acc[i][5], acc[i][6], acc[i][7]);
        }
    }
}

// ---------------------------------------------------------------------------
// Counting sort of edges by dst (shared by both layers)
// ---------------------------------------------------------------------------
__global__ __launch_bounds__(256) void hist_kernel(
    const int* __restrict__ ei, int* __restrict__ cnt, int E)
{
    int e = blockIdx.x * 256 + threadIdx.x;
    if (e < E) atomicAdd(cnt + ei[E + e], 1);
}

// single-block exclusive scan over N counters -> start[0..N], cursor copy
__global__ __launch_bounds__(1024) void scan_kernel(
    const int* __restrict__ cnt, int* __restrict__ start,
    int* __restrict__ cursor, int N, int E)
{
    __shared__ int lds[1024];
    __shared__ int carry;
    int tid = threadIdx.x;
    if (tid == 0) carry = 0;
    __syncthreads();
    for (int base = 0; base < N; base += 1024) {
        int i = base + tid;
        int v = (i < N) ? cnt[i] : 0;
        lds[tid] = v;
        __syncthreads();
        for (int off = 1; off < 1024; off <<= 1) {
            int t = (tid >= off) ? lds[tid - off] : 0;
            __syncthreads();
            lds[tid] += t;
            __syncthreads();
        }
        int excl = lds[tid] - v + carry;
        if (i < N) { start[i] = excl; cursor[i] = excl; }
        __syncthreads();                 // all reads of carry/lds done
        if (tid == 0) carry += lds[1023];
        __syncthreads();
    }
    if (tid == 0) start[N] = E;
}

__global__ __launch_bounds__(256) void scatter_kernel(
    const int* __restrict__ ei, int* __restrict__ cursor,
    int* __restrict__ sorted_src, int E)
{
    int e = blockIdx.x * 256 + threadIdx.x;
    if (e < E) {
        int pos = atomicAdd(cursor + ei[E + e], 1);
        sorted_src[pos] = ei[e];
    }
}

// ---------------------------------------------------------------------------
// Fused score+softmax+aggregate: one wave per dst node, single pass.
// out[dst] = (sum_e exp(s_e) * xl[src_e]) / (sum_e exp(s_e)) + bias
// Self-loop handled inline. H=2: lanes 0-31 = head 0, lanes 32-63 = head 1.
// ---------------------------------------------------------------------------
template <int H>
__global__ __launch_bounds__(256) void gat_fused_kernel(
    const float* __restrict__ xl, const float* __restrict__ xr,
    const float* __restrict__ att, const float* __restrict__ bias,
    const int* __restrict__ start, const int* __restrict__ sorted_src,
    float* __restrict__ out, int N)
{
    int node = blockIdx.x * 4 + (threadIdx.x >> 6);
    if (node >= N) return;
    int lane = threadIdx.x & 63;

    float2 b     = *(const float2*)(xr + (size_t)node * 128 + lane * 2);
    float2 selfa = *(const float2*)(xl + (size_t)node * 128 + lane * 2);
    float att0 = att[lane * 2];
    float att1 = att[lane * 2 + 1];

    float2 acc = make_float2(0.f, 0.f);
    float den = 0.f;

    // self-loop edge (src = dst)
    {
        float p = lrelu(selfa.x + b.x) * att0 + lrelu(selfa.y + b.y) * att1;
#pragma unroll
        for (int m = 1; m <= (H == 2 ? 16 : 32); m <<= 1) p += __shfl_xor(p, m, 64);
        float ex = __expf(p);
        den += ex;
        acc.x += ex * selfa.x;
        acc.y += ex * selfa.y;
    }

    int s0 = start[node], s1 = start[node + 1];
    for (int s = s0; s < s1; ++s) {
        int src = sorted_src[s];
        float2 a = *(const float2*)(xl + (size_t)src * 128 + lane * 2);
        float p = lrelu(a.x + b.x) * att0 + lrelu(a.y + b.y) * att1;
#pragma unroll
        for (int m = 1; m <= (H == 2 ? 16 : 32); m <<= 1) p += __shfl_xor(p, m, 64);
        float ex = __expf(p);
        den += ex;
        acc.x += ex * a.x;
        acc.y += ex * a.y;
    }

    float inv = 1.0f / den;   // per-lane den equals its head's denominator
    float2 o;
    o.x = acc.x * inv + bias[lane * 2];
    o.y = acc.y * inv + bias[lane * 2 + 1];
    *(float2*)(out + (size_t)node * 128 + lane * 2) = o;
}

// ---------------------------------------------------------------------------
extern "C" void kernel_launch(void* const* d_in, const int* in_sizes, int n_in,
                              void* d_out, int out_size, void* d_ws, size_t ws_size,
                              hipStream_t stream)
{
    const float* x    = (const float*)d_in[0];
    const int*   ei   = (const int*)d_in[1];
    const float* Wl1  = (const float*)d_in[3];
    const float* Wr1  = (const float*)d_in[4];
    const float* att1 = (const float*)d_in[5];
    const float* b1   = (const float*)d_in[6];
    const float* Wl2  = (const float*)d_in[7];
    const float* Wr2  = (const float*)d_in[8];
    const float* att2 = (const float*)d_in[9];
    const float* b2   = (const float*)d_in[10];
    float* out = (float*)d_out;

    const int N = in_sizes[0] / 128;
    const int E = in_sizes[1] / 2;

    const size_t nf = (size_t)N * 128;
    float* xl = (float*)d_ws;            // N*128 f32
    float* xr = xl + nf;                 // N*128 f32
    float* h  = xr + nf;                 // N*128 f32
    int* cnt        = (int*)(h + nf);    // N
    int* start      = cnt + N;           // N+1
    int* cursor     = start + N + 1;     // N
    int* sorted_src = cursor + N;        // E

    const int gemm_gx    = (N + 63) / 64;
    const int edge_grid  = (E + 255) / 256;
    const int node_grid  = (N + 3) / 4;

    // ---- edge sort by dst (shared by both layers) ----
    hipMemsetAsync(cnt, 0, (size_t)N * sizeof(int), stream);
    hist_kernel<<<edge_grid, 256, 0, stream>>>(ei, cnt, E);
    scan_kernel<<<1, 1024, 0, stream>>>(cnt, start, cursor, N, E);
    scatter_kernel<<<edge_grid, 256, 0, stream>>>(ei, cursor, sorted_src, E);

    // ---- Layer 1: heads=2, ch=64 ----
    gemm2_kernel<<<dim3(gemm_gx, 2), 256, 0, stream>>>(x, Wl1, Wr1, xl, xr, N);
    gat_fused_kernel<2><<<node_grid, 256, 0, stream>>>(xl, xr, att1, b1, start, sorted_src, h, N);

    // ---- Layer 2: heads=1, ch=128 ----
    gemm2_kernel<<<dim3(gemm_gx, 2), 256, 0, stream>>>(h, Wl2, Wr2, xl, xr, N);
    gat_fused_kernel<1><<<node_grid, 256, 0, stream>>>(xl, xr, att2, b2, start, sorted_src, out, N);
}

// Round 3
// 603.724 us; speedup vs baseline: 3.2698x; 1.0432x over previous
//
#include <hip/hip_runtime.h>

#define NEG_SLOPE 0.2f

__device__ __forceinline__ float lrelu(float v) {
    return v > 0.0f ? v : NEG_SLOPE * v;
}

// ---------------------------------------------------------------------------
// GEMM: C0 = A @ W0, C1 = A @ W1   (A: [N,128], W: [128,128])
// 128x128 tile, 8x8 microtile, K-chunks of 32. FMA:LDS = 4:1.
// ---------------------------------------------------------------------------
__global__ __launch_bounds__(256) void gemm2_kernel(
    const float* __restrict__ A,
    const float* __restrict__ W0, const float* __restrict__ W1,
    float* __restrict__ C0, float* __restrict__ C1, int N)
{
    const float* W = blockIdx.y ? W1 : W0;
    float* C = blockIdx.y ? C1 : C0;

    __shared__ float lds_a[128][33];   // +1 pad: a-reads hit 4 distinct banks, 16-way broadcast
    __shared__ float lds_w[32][128];

    const int tid = threadIdx.x;
    const int row0 = blockIdx.x * 128;
    const int tx = tid & 15;    // cols tx*8 .. tx*8+7
    const int ty = tid >> 4;    // rows ty*8 .. ty*8+7

    float acc[8][8];
#pragma unroll
    for (int i = 0; i < 8; i++)
#pragma unroll
        for (int j = 0; j < 8; j++) acc[i][j] = 0.0f;

    for (int k0 = 0; k0 < 128; k0 += 32) {
        // A tile: 128 rows x 32 k = 1024 float4, 4 per thread
        {
#pragma unroll
            for (int rep = 0; rep < 4; rep++) {
                int idx = tid + rep * 256;
                int r  = idx >> 3;
                int c4 = idx & 7;
                int gr = row0 + r;
                float4 v = make_float4(0.f, 0.f, 0.f, 0.f);
                if (gr < N) v = *(const float4*)(A + (size_t)gr * 128 + k0 + c4 * 4);
                *(float4*)&lds_a[r][c4 * 4] = v;
            }
        }
        // W tile: 32 rows x 128 cols = 1024 float4, 4 per thread
        {
#pragma unroll
            for (int rep = 0; rep < 4; rep++) {
                int idx = tid + rep * 256;
                int r  = idx >> 5;
                int c4 = idx & 31;
                *(float4*)&lds_w[r][c4 * 4] = *(const float4*)(W + (size_t)(k0 + r) * 128 + c4 * 4);
            }
        }
        __syncthreads();

#pragma unroll
        for (int kk = 0; kk < 32; kk++) {
            float a[8];
#pragma unroll
            for (int i = 0; i < 8; i++) a[i] = lds_a[ty * 8 + i][kk];
            float w[8];
            *(float4*)&w[0] = *(float4*)&lds_w[kk][tx * 8];
            *(float4*)&w[4] = *(float4*)&lds_w[kk][tx * 8 + 4];
#pragma unroll
            for (int i = 0; i < 8; i++)
#pragma unroll
                for (int j = 0; j < 8; j++)
                    acc[i][j] += a[i] * w[j];
        }
        __syncthreads();
    }

#pragma unroll
    for (int i = 0; i < 8; i++) {
        int gr = row0 + ty * 8 + i;
        if (gr < N) {
            *(float4*)(C + (size_t)gr * 128 + tx * 8)     = make_float4(acc[i][0], acc[i][1], acc[i][2], acc[i][3]);
            *(float4*)(C + (size_t)gr * 128 + tx * 8 + 4) = make_float4(acc[i][4], acc[i][5], acc[i][6], acc[i][7]);
        }
    }
}

// ---------------------------------------------------------------------------
// Counting sort of edges by dst (shared by both layers)
// ---------------------------------------------------------------------------
__global__ __launch_bounds__(256) void hist_kernel(
    const int* __restrict__ ei, int* __restrict__ cnt, int E)
{
    int e = blockIdx.x * 256 + threadIdx.x;
    if (e < E) atomicAdd(cnt + ei[E + e], 1);
}

__global__ __launch_bounds__(1024) void scan_kernel(
    const int* __restrict__ cnt, int* __restrict__ start,
    int* __restrict__ cursor, int N, int E)
{
    __shared__ int lds[1024];
    __shared__ int carry;
    int tid = threadIdx.x;
    if (tid == 0) carry = 0;
    __syncthreads();
    for (int base = 0; base < N; base += 1024) {
        int i = base + tid;
        int v = (i < N) ? cnt[i] : 0;
        lds[tid] = v;
        __syncthreads();
        for (int off = 1; off < 1024; off <<= 1) {
            int t = (tid >= off) ? lds[tid - off] : 0;
            __syncthreads();
            lds[tid] += t;
            __syncthreads();
        }
        int excl = lds[tid] - v + carry;
        if (i < N) { start[i] = excl; cursor[i] = excl; }
        __syncthreads();
        if (tid == 0) carry += lds[1023];
        __syncthreads();
    }
    if (tid == 0) start[N] = E;
}

__global__ __launch_bounds__(256) void scatter_kernel(
    const int* __restrict__ ei, int* __restrict__ cursor,
    int* __restrict__ sorted_src, int E)
{
    int e = blockIdx.x * 256 + threadIdx.x;
    if (e < E) {
        int pos = atomicAdd(cursor + ei[E + e], 1);
        sorted_src[pos] = ei[e];
    }
}

// ---------------------------------------------------------------------------
// Fused score+softmax+aggregate: one wave per dst node, single pass,
// edge loop unrolled by 4 for memory-level parallelism + shuffle-chain ILP.
// ---------------------------------------------------------------------------
template <int H>
__global__ __launch_bounds__(256) void gat_fused_kernel(
    const float* __restrict__ xl, const float* __restrict__ xr,
    const float* __restrict__ att, const float* __restrict__ bias,
    const int* __restrict__ start, const int* __restrict__ sorted_src,
    float* __restrict__ out, int N)
{
    int node = blockIdx.x * 4 + (threadIdx.x >> 6);
    if (node >= N) return;
    int lane = threadIdx.x & 63;

    float2 b     = *(const float2*)(xr + (size_t)node * 128 + lane * 2);
    float2 selfa = *(const float2*)(xl + (size_t)node * 128 + lane * 2);
    float att0 = att[lane * 2];
    float att1 = att[lane * 2 + 1];
    const int RED = (H == 2) ? 16 : 32;   // xor masks 1..RED

    float2 acc = make_float2(0.f, 0.f);
    float den = 0.f;

    // self-loop edge (src = dst)
    {
        float p = lrelu(selfa.x + b.x) * att0 + lrelu(selfa.y + b.y) * att1;
#pragma unroll
        for (int m = 1; m <= 32; m <<= 1) {
            if (m <= RED) p += __shfl_xor(p, m, 64);
        }
        float ex = __expf(p);
        den += ex;
        acc.x += ex * selfa.x;
        acc.y += ex * selfa.y;
    }

    int s0 = start[node], s1 = start[node + 1];
    int s = s0;
    for (; s + 4 <= s1; s += 4) {
        int i0 = sorted_src[s];
        int i1 = sorted_src[s + 1];
        int i2 = sorted_src[s + 2];
        int i3 = sorted_src[s + 3];
        float2 a0 = *(const float2*)(xl + (size_t)i0 * 128 + lane * 2);
        float2 a1 = *(const float2*)(xl + (size_t)i1 * 128 + lane * 2);
        float2 a2 = *(const float2*)(xl + (size_t)i2 * 128 + lane * 2);
        float2 a3 = *(const float2*)(xl + (size_t)i3 * 128 + lane * 2);
        float p0 = lrelu(a0.x + b.x) * att0 + lrelu(a0.y + b.y) * att1;
        float p1 = lrelu(a1.x + b.x) * att0 + lrelu(a1.y + b.y) * att1;
        float p2 = lrelu(a2.x + b.x) * att0 + lrelu(a2.y + b.y) * att1;
        float p3 = lrelu(a3.x + b.x) * att0 + lrelu(a3.y + b.y) * att1;
#pragma unroll
        for (int m = 1; m <= 32; m <<= 1) {
            if (m <= RED) {
                p0 += __shfl_xor(p0, m, 64);
                p1 += __shfl_xor(p1, m, 64);
                p2 += __shfl_xor(p2, m, 64);
                p3 += __shfl_xor(p3, m, 64);
            }
        }
        float e0 = __expf(p0);
        float e1 = __expf(p1);
        float e2 = __expf(p2);
        float e3 = __expf(p3);
        den += (e0 + e1) + (e2 + e3);
        acc.x += e0 * a0.x + e1 * a1.x + e2 * a2.x + e3 * a3.x;
        acc.y += e0 * a0.y + e1 * a1.y + e2 * a2.y + e3 * a3.y;
    }
    for (; s < s1; ++s) {
        int src = sorted_src[s];
        float2 a = *(const float2*)(xl + (size_t)src * 128 + lane * 2);
        float p = lrelu(a.x + b.x) * att0 + lrelu(a.y + b.y) * att1;
#pragma unroll
        for (int m = 1; m <= 32; m <<= 1) {
            if (m <= RED) p += __shfl_xor(p, m, 64);
        }
        float ex = __expf(p);
        den += ex;
        acc.x += ex * a.x;
        acc.y += ex * a.y;
    }

    float inv = 1.0f / den;
    float2 o;
    o.x = acc.x * inv + bias[lane * 2];
    o.y = acc.y * inv + bias[lane * 2 + 1];
    *(float2*)(out + (size_t)node * 128 + lane * 2) = o;
}

// ---------------------------------------------------------------------------
extern "C" void kernel_launch(void* const* d_in, const int* in_sizes, int n_in,
                              void* d_out, int out_size, void* d_ws, size_t ws_size,
                              hipStream_t stream)
{
    const float* x    = (const float*)d_in[0];
    const int*   ei   = (const int*)d_in[1];
    const float* Wl1  = (const float*)d_in[3];
    const float* Wr1  = (const float*)d_in[4];
    const float* att1 = (const float*)d_in[5];
    const float* b1   = (const float*)d_in[6];
    const float* Wl2  = (const float*)d_in[7];
    const float* Wr2  = (const float*)d_in[8];
    const float* att2 = (const float*)d_in[9];
    const float* b2   = (const float*)d_in[10];
    float* out = (float*)d_out;

    const int N = in_sizes[0] / 128;
    const int E = in_sizes[1] / 2;

    const size_t nf = (size_t)N * 128;
    float* xl = (float*)d_ws;            // N*128 f32
    float* xr = xl + nf;                 // N*128 f32
    float* h  = xr + nf;                 // N*128 f32
    int* cnt        = (int*)(h + nf);    // N
    int* start      = cnt + N;           // N+1
    int* cursor     = start + N + 1;     // N
    int* sorted_src = cursor + N;        // E

    const int gemm_gx   = (N + 127) / 128;
    const int edge_grid = (E + 255) / 256;
    const int node_grid = (N + 3) / 4;

    // ---- edge sort by dst (shared by both layers) ----
    hipMemsetAsync(cnt, 0, (size_t)N * sizeof(int), stream);
    hist_kernel<<<edge_grid, 256, 0, stream>>>(ei, cnt, E);
    scan_kernel<<<1, 1024, 0, stream>>>(cnt, start, cursor, N, E);
    scatter_kernel<<<edge_grid, 256, 0, stream>>>(ei, cursor, sorted_src, E);

    // ---- Layer 1: heads=2, ch=64 ----
    gemm2_kernel<<<dim3(gemm_gx, 2), 256, 0, stream>>>(x, Wl1, Wr1, xl, xr, N);
    gat_fused_kernel<2><<<node_grid, 256, 0, stream>>>(xl, xr, att1, b1, start, sorted_src, h, N);

    // ---- Layer 2: heads=1, ch=128 ----
    gemm2_kernel<<<dim3(gemm_gx, 2), 256, 0, stream>>>(h, Wl2, Wr2, xl, xr, N);
    gat_fused_kernel<1><<<node_grid, 256, 0, stream>>>(xl, xr, att2, b2, start, sorted_src, out, N);
}

// Round 4
// 410.750 us; speedup vs baseline: 4.8061x; 1.4698x over previous
//
#include <hip/hip_runtime.h>

#define NEG_SLOPE 0.2f

typedef short bf16x8 __attribute__((ext_vector_type(8)));
typedef float f32x4 __attribute__((ext_vector_type(4)));

__device__ __forceinline__ float lrelu(float v) { return v > 0.0f ? v : NEG_SLOPE * v; }

// round-to-nearest-even f32 -> bf16 bits (values are finite; no NaN handling needed)
__device__ __forceinline__ unsigned short f2bf(float f) {
    union { float f; unsigned u; } v; v.f = f;
    unsigned r = v.u + 0x7fffu + ((v.u >> 16) & 1u);
    return (unsigned short)(r >> 16);
}
__device__ __forceinline__ float bf2f(unsigned short b) {
    union { unsigned u; float f; } v; v.u = ((unsigned)b) << 16;
    return v.f;
}

// ---------------------------------------------------------------------------
// Split + transpose the 4 weight matrices: Wt_hi/lo[m][n][k] = split(W[m][k][n])
// ---------------------------------------------------------------------------
__global__ __launch_bounds__(256) void wsplit_kernel(
    const float* __restrict__ W0, const float* __restrict__ W1,
    const float* __restrict__ W2, const float* __restrict__ W3,
    unsigned short* __restrict__ wt_hi, unsigned short* __restrict__ wt_lo)
{
    int idx = blockIdx.x * 256 + threadIdx.x;   // 4*128*128 total
    int m = idx >> 14;
    int k = (idx >> 7) & 127;
    int n = idx & 127;
    const float* W = (m == 0) ? W0 : (m == 1) ? W1 : (m == 2) ? W2 : W3;
    float f = W[k * 128 + n];
    unsigned short h = f2bf(f);
    unsigned short l = f2bf(f - bf2f(h));
    wt_hi[m * 16384 + n * 128 + k] = h;
    wt_lo[m * 16384 + n * 128 + k] = l;
}

// x (fp32, [N,128]) -> hi/lo bf16 pair, same layout
__global__ __launch_bounds__(256) void xsplit_kernel(
    const float* __restrict__ x, unsigned short* __restrict__ xh,
    unsigned short* __restrict__ xlo, int total)
{
    int i = blockIdx.x * 256 + threadIdx.x;
    if (i * 2 < total) {
        float2 f = *(const float2*)(x + (size_t)i * 2);
        ushort2 h, l;
        h.x = f2bf(f.x); l.x = f2bf(f.x - bf2f(h.x));
        h.y = f2bf(f.y); l.y = f2bf(f.y - bf2f(h.y));
        *(ushort2*)(xh  + (size_t)i * 2) = h;
        *(ushort2*)(xlo + (size_t)i * 2) = l;
    }
}

// ---------------------------------------------------------------------------
// Split-bf16 MFMA GEMM: C = A @ W  (A: [N,128] as hi/lo bf16, Wt: [n][k] hi/lo)
// C ~= Ah*Wh + Ah*Wl + Al*Wh  (fp32 accumulate), error ~2^-17.
// block 256 = 4 waves; wave covers 32 rows x 128 cols; 16x16x32 MFMA.
// ---------------------------------------------------------------------------
__global__ __launch_bounds__(256) void gemm_mfma_kernel(
    const unsigned short* __restrict__ Ahi, const unsigned short* __restrict__ Alo,
    const unsigned short* __restrict__ Wt0hi, const unsigned short* __restrict__ Wt0lo,
    const unsigned short* __restrict__ Wt1hi, const unsigned short* __restrict__ Wt1lo,
    float* __restrict__ C0, float* __restrict__ C1, int N)
{
    const unsigned short* Whi = blockIdx.y ? Wt1hi : Wt0hi;
    const unsigned short* Wlo = blockIdx.y ? Wt1lo : Wt0lo;
    float* C = blockIdx.y ? C1 : C0;

    // row stride 136 shorts = 272 B (=17*16): 16B-aligned rows, 2-way bank alias (free)
    __shared__ unsigned short ldsW[2][128][136];

    const int tid = threadIdx.x;
    {   // stage both splits of W: thread -> row n = tid>>1, half = tid&1 (64 shorts)
        int n = tid >> 1, half = tid & 1;
        const float4* gh = (const float4*)(Whi + n * 128 + half * 64);
        const float4* gl = (const float4*)(Wlo + n * 128 + half * 64);
        float4* dh = (float4*)&ldsW[0][n][half * 64];
        float4* dl = (float4*)&ldsW[1][n][half * 64];
#pragma unroll
        for (int j = 0; j < 8; j++) { dh[j] = gh[j]; dl[j] = gl[j]; }
    }

    const int wave = tid >> 6;
    const int lane = tid & 63;
    const int mrow = lane & 15;      // A row / B col / D col index
    const int quad = lane >> 4;
    const int rbase = blockIdx.x * 128 + wave * 32;

    // prefetch all A fragments (2 row-tiles x 4 K-steps, hi+lo)
    bf16x8 ah[2][4], al[2][4];
#pragma unroll
    for (int rt = 0; rt < 2; rt++) {
        int r = rbase + rt * 16 + mrow;
        if (r > N - 1) r = N - 1;
        const unsigned short* pa = Ahi + (size_t)r * 128 + quad * 8;
        const unsigned short* pl = Alo + (size_t)r * 128 + quad * 8;
#pragma unroll
        for (int s = 0; s < 4; s++) {
            ah[rt][s] = *(const bf16x8*)(pa + s * 32);
            al[rt][s] = *(const bf16x8*)(pl + s * 32);
        }
    }

    f32x4 acc[2][8];
#pragma unroll
    for (int rt = 0; rt < 2; rt++)
#pragma unroll
        for (int c = 0; c < 8; c++) acc[rt][c] = (f32x4){0.f, 0.f, 0.f, 0.f};

    __syncthreads();

#pragma unroll
    for (int s = 0; s < 4; s++) {
#pragma unroll
        for (int c = 0; c < 8; c++) {
            bf16x8 bh = *(const bf16x8*)&ldsW[0][c * 16 + mrow][s * 32 + quad * 8];
            bf16x8 bl = *(const bf16x8*)&ldsW[1][c * 16 + mrow][s * 32 + quad * 8];
#pragma unroll
            for (int rt = 0; rt < 2; rt++) {
                acc[rt][c] = __builtin_amdgcn_mfma_f32_16x16x32_bf16(ah[rt][s], bh, acc[rt][c], 0, 0, 0);
                acc[rt][c] = __builtin_amdgcn_mfma_f32_16x16x32_bf16(ah[rt][s], bl, acc[rt][c], 0, 0, 0);
                acc[rt][c] = __builtin_amdgcn_mfma_f32_16x16x32_bf16(al[rt][s], bh, acc[rt][c], 0, 0, 0);
            }
        }
    }

    // D mapping (m89-verified): col = lane&15, row = quad*4 + reg
#pragma unroll
    for (int rt = 0; rt < 2; rt++) {
#pragma unroll
        for (int i = 0; i < 4; i++) {
            int r = rbase + rt * 16 + quad * 4 + i;
            if (r < N) {
                float* cr = C + (size_t)r * 128 + mrow;
#pragma unroll
                for (int c = 0; c < 8; c++) cr[c * 16] = acc[rt][c][i];
            }
        }
    }
}

// ---------------------------------------------------------------------------
// Counting sort of edges by dst — hist, hierarchical scan, scatter
// ---------------------------------------------------------------------------
__global__ __launch_bounds__(256) void hist_kernel(
    const int* __restrict__ ei, int* __restrict__ cnt, int E)
{
    int e = blockIdx.x * 256 + threadIdx.x;
    if (e < E) atomicAdd(cnt + ei[E + e], 1);
}

__global__ __launch_bounds__(256) void blockscan_kernel(
    const int* __restrict__ cnt, int* __restrict__ excl,
    int* __restrict__ bsum, int N)
{
    __shared__ int s[256];
    int tid = threadIdx.x;
    int i = blockIdx.x * 256 + tid;
    int v = (i < N) ? cnt[i] : 0;
    s[tid] = v;
    __syncthreads();
    for (int off = 1; off < 256; off <<= 1) {
        int t = (tid >= off) ? s[tid - off] : 0;
        __syncthreads();
        s[tid] += t;
        __syncthreads();
    }
    if (i < N) excl[i] = s[tid] - v;
    if (tid == 255) bsum[blockIdx.x] = s[255];
}

__global__ __launch_bounds__(256) void topscan_kernel(
    const int* __restrict__ bsum, int* __restrict__ boff, int G)
{
    __shared__ int s[256];
    int tid = threadIdx.x;
    int v = (tid < G) ? bsum[tid] : 0;
    s[tid] = v;
    __syncthreads();
    for (int off = 1; off < 256; off <<= 1) {
        int t = (tid >= off) ? s[tid - off] : 0;
        __syncthreads();
        s[tid] += t;
        __syncthreads();
    }
    if (tid < G) boff[tid] = s[tid] - v;
}

__global__ __launch_bounds__(256) void addoff_kernel(
    int* __restrict__ start, int* __restrict__ cursor,
    const int* __restrict__ boff, int N, int E)
{
    int i = blockIdx.x * 256 + threadIdx.x;
    if (i < N) {
        int t = start[i] + boff[blockIdx.x];
        start[i] = t;
        cursor[i] = t;
    }
    if (i == 0) start[N] = E;
}

__global__ __launch_bounds__(256) void scatter_kernel(
    const int* __restrict__ ei, int* __restrict__ cursor,
    int* __restrict__ sorted_src, int E)
{
    int e = blockIdx.x * 256 + threadIdx.x;
    if (e < E) {
        int pos = atomicAdd(cursor + ei[E + e], 1);
        sorted_src[pos] = ei[e];
    }
}

// ---------------------------------------------------------------------------
// Fused score+softmax+aggregate: one wave per dst node, single pass,
// unrolled 8/4/1 for gather MLP. BFOUT: write split-bf16 h for the next GEMM.
// ---------------------------------------------------------------------------
template <int H, bool BFOUT>
__global__ __launch_bounds__(256) void gat_fused_kernel(
    const float* __restrict__ xl, const float* __restrict__ xr,
    const float* __restrict__ att, const float* __restrict__ bias,
    const int* __restrict__ start, const int* __restrict__ sorted_src,
    float* __restrict__ outf, unsigned short* __restrict__ oh,
    unsigned short* __restrict__ ol, int N)
{
    int node = blockIdx.x * 4 + (threadIdx.x >> 6);
    if (node >= N) return;
    int lane = threadIdx.x & 63;

    float2 b     = *(const float2*)(xr + (size_t)node * 128 + lane * 2);
    float2 selfa = *(const float2*)(xl + (size_t)node * 128 + lane * 2);
    float att0 = att[lane * 2];
    float att1 = att[lane * 2 + 1];
    const int RED = (H == 2) ? 16 : 32;

    float2 acc = make_float2(0.f, 0.f);
    float den = 0.f;

    // self-loop
    {
        float p = lrelu(selfa.x + b.x) * att0 + lrelu(selfa.y + b.y) * att1;
#pragma unroll
        for (int m = 1; m <= 32; m <<= 1)
            if (m <= RED) p += __shfl_xor(p, m, 64);
        float ex = __expf(p);
        den += ex;
        acc.x += ex * selfa.x;
        acc.y += ex * selfa.y;
    }

    int s0 = start[node], s1 = start[node + 1];
    int s = s0;
    for (; s + 8 <= s1; s += 8) {
        int idx[8]; float2 a[8]; float p[8];
#pragma unroll
        for (int j = 0; j < 8; j++) idx[j] = sorted_src[s + j];
#pragma unroll
        for (int j = 0; j < 8; j++) a[j] = *(const float2*)(xl + (size_t)idx[j] * 128 + lane * 2);
#pragma unroll
        for (int j = 0; j < 8; j++)
            p[j] = lrelu(a[j].x + b.x) * att0 + lrelu(a[j].y + b.y) * att1;
#pragma unroll
        for (int m = 1; m <= 32; m <<= 1)
            if (m <= RED) {
#pragma unroll
                for (int j = 0; j < 8; j++) p[j] += __shfl_xor(p[j], m, 64);
            }
#pragma unroll
        for (int j = 0; j < 8; j++) {
            float e = __expf(p[j]);
            den += e;
            acc.x += e * a[j].x;
            acc.y += e * a[j].y;
        }
    }
    for (; s + 4 <= s1; s += 4) {
        int idx[4]; float2 a[4]; float p[4];
#pragma unroll
        for (int j = 0; j < 4; j++) idx[j] = sorted_src[s + j];
#pragma unroll
        for (int j = 0; j < 4; j++) a[j] = *(const float2*)(xl + (size_t)idx[j] * 128 + lane * 2);
#pragma unroll
        for (int j = 0; j < 4; j++)
            p[j] = lrelu(a[j].x + b.x) * att0 + lrelu(a[j].y + b.y) * att1;
#pragma unroll
        for (int m = 1; m <= 32; m <<= 1)
            if (m <= RED) {
#pragma unroll
                for (int j = 0; j < 4; j++) p[j] += __shfl_xor(p[j], m, 64);
            }
#pragma unroll
        for (int j = 0; j < 4; j++) {
            float e = __expf(p[j]);
            den += e;
            acc.x += e * a[j].x;
            acc.y += e * a[j].y;
        }
    }
    for (; s < s1; ++s) {
        int src = sorted_src[s];
        float2 a = *(const float2*)(xl + (size_t)src * 128 + lane * 2);
        float p = lrelu(a.x + b.x) * att0 + lrelu(a.y + b.y) * att1;
#pragma unroll
        for (int m = 1; m <= 32; m <<= 1)
            if (m <= RED) p += __shfl_xor(p, m, 64);
        float ex = __expf(p);
        den += ex;
        acc.x += ex * a.x;
        acc.y += ex * a.y;
    }

    float inv = 1.0f / den;
    float ox = acc.x * inv + bias[lane * 2];
    float oy = acc.y * inv + bias[lane * 2 + 1];
    if (BFOUT) {
        unsigned short hx = f2bf(ox), hy = f2bf(oy);
        unsigned short lx = f2bf(ox - bf2f(hx)), ly = f2bf(oy - bf2f(hy));
        ushort2 h2; h2.x = hx; h2.y = hy;
        ushort2 l2; l2.x = lx; l2.y = ly;
        *(ushort2*)(oh + (size_t)node * 128 + lane * 2) = h2;
        *(ushort2*)(ol + (size_t)node * 128 + lane * 2) = l2;
    } else {
        *(float2*)(outf + (size_t)node * 128 + lane * 2) = make_float2(ox, oy);
    }
}

// ---------------------------------------------------------------------------
extern "C" void kernel_launch(void* const* d_in, const int* in_sizes, int n_in,
                              void* d_out, int out_size, void* d_ws, size_t ws_size,
                              hipStream_t stream)
{
    const float* x    = (const float*)d_in[0];
    const int*   ei   = (const int*)d_in[1];
    const float* Wl1  = (const float*)d_in[3];
    const float* Wr1  = (const float*)d_in[4];
    const float* att1 = (const float*)d_in[5];
    const float* b1   = (const float*)d_in[6];
    const float* Wl2  = (const float*)d_in[7];
    const float* Wr2  = (const float*)d_in[8];
    const float* att2 = (const float*)d_in[9];
    const float* b2   = (const float*)d_in[10];
    float* out = (float*)d_out;

    const int N = in_sizes[0] / 128;
    const int E = in_sizes[1] / 2;

    const size_t nf = (size_t)N * 128;
    float* xl = (float*)d_ws;                         // N*128 f32
    float* xr = xl + nf;                              // N*128 f32
    unsigned short* xh  = (unsigned short*)(xr + nf); // N*128 bf16 (A_hi; reused as h_hi)
    unsigned short* xlo = xh + nf;                    // N*128 bf16 (A_lo; reused as h_lo)
    unsigned short* wt_hi = xlo + nf;                 // 4*128*128 bf16 (transposed W hi)
    unsigned short* wt_lo = wt_hi + 4 * 16384;        // 4*128*128 bf16
    int* cnt        = (int*)(wt_lo + 4 * 16384);      // N
    int* start      = cnt + N;                        // N+1
    int* cursor     = start + N + 1;                  // N
    int* bsum       = cursor + N;                     // 256
    int* boff       = bsum + 256;                     // 256
    int* sorted_src = boff + 256;                     // E

    const int G          = (N + 255) / 256;           // scan blocks (<=256)
    const int edge_grid  = (E + 255) / 256;
    const int node_grid  = (N + 3) / 4;
    const int gemm_gx    = (N + 127) / 128;
    const int split_grid = (int)((nf / 2 + 255) / 256);

    // ---- precompute: weight transpose+split, x split ----
    wsplit_kernel<<<256, 256, 0, stream>>>(Wl1, Wr1, Wl2, Wr2, wt_hi, wt_lo);
    xsplit_kernel<<<split_grid, 256, 0, stream>>>(x, xh, xlo, (int)nf);

    // ---- edge sort by dst (shared by both layers) ----
    hipMemsetAsync(cnt, 0, (size_t)N * sizeof(int), stream);
    hist_kernel<<<edge_grid, 256, 0, stream>>>(ei, cnt, E);
    blockscan_kernel<<<G, 256, 0, stream>>>(cnt, start, bsum, N);
    topscan_kernel<<<1, 256, 0, stream>>>(bsum, boff, G);
    addoff_kernel<<<G, 256, 0, stream>>>(start, cursor, boff, N, E);
    scatter_kernel<<<edge_grid, 256, 0, stream>>>(ei, cursor, sorted_src, E);

    // ---- Layer 1: heads=2, ch=64 ----
    gemm_mfma_kernel<<<dim3(gemm_gx, 2), 256, 0, stream>>>(
        xh, xlo, wt_hi + 0 * 16384, wt_lo + 0 * 16384,
        wt_hi + 1 * 16384, wt_lo + 1 * 16384, xl, xr, N);
    gat_fused_kernel<2, true><<<node_grid, 256, 0, stream>>>(
        xl, xr, att1, b1, start, sorted_src, nullptr, xh, xlo, N);

    // ---- Layer 2: heads=1, ch=128 ----  (A = h, already split in xh/xlo)
    gemm_mfma_kernel<<<dim3(gemm_gx, 2), 256, 0, stream>>>(
        xh, xlo, wt_hi + 2 * 16384, wt_lo + 2 * 16384,
        wt_hi + 3 * 16384, wt_lo + 3 * 16384, xl, xr, N);
    gat_fused_kernel<1, false><<<node_grid, 256, 0, stream>>>(
        xl, xr, att2, b2, start, sorted_src, out, nullptr, nullptr, N);
}